// Round 6
// baseline (384.321 us; speedup 1.0000x reference)
//
#include <hip/hip_runtime.h>
#include <stdint.h>

#define Bb 2
#define Td 2048
#define Sd 2048
#define Dd 2048
#define Nh 16
#define Kvh 4
#define Hd 128
// G = Nh/Kvh = 4

typedef unsigned short u16;
typedef short bf16x8 __attribute__((ext_vector_type(8)));
typedef float f32x4 __attribute__((ext_vector_type(4)));

__device__ __forceinline__ u16 f2bf(float f) {
  union { float f; unsigned u; } v; v.f = f;
  v.u += 0x7FFF + ((v.u >> 16) & 1);   // round-to-nearest-even
  return (u16)(v.u >> 16);
}
__device__ __forceinline__ float bf2f(u16 h) {
  union { unsigned u; float f; } v; v.u = ((unsigned)h) << 16;
  return v.f;
}

// ---------------- f32 -> bf16 bulk convert (8 elems/thread, 16B stores) ----
__global__ __launch_bounds__(256) void k_convert(const float* __restrict__ in,
                                                 u16* __restrict__ out, int n8) {
  int i = blockIdx.x * 256 + threadIdx.x;
  if (i >= n8) return;
  const float4* p = (const float4*)in;
  float4 a = p[(size_t)i * 2], b = p[(size_t)i * 2 + 1];
  ushort4 r0, r1;
  r0.x = f2bf(a.x); r0.y = f2bf(a.y); r0.z = f2bf(a.z); r0.w = f2bf(a.w);
  r1.x = f2bf(b.x); r1.y = f2bf(b.y); r1.z = f2bf(b.z); r1.w = f2bf(b.w);
  ((ushort4*)out)[(size_t)i * 2] = r0;
  ((ushort4*)out)[(size_t)i * 2 + 1] = r1;
}

// ---------------- tiled transpose f32[R,C] -> bf16[C,R] --------------------
__global__ __launch_bounds__(256) void k_transpose_f32_bf16(const float* __restrict__ in,
                                                            u16* __restrict__ out,
                                                            int R, int C) {
  __shared__ u16 tile[32][33];
  int c0 = blockIdx.x * 32, r0 = blockIdx.y * 32;
  int tx = threadIdx.x & 31, ty = threadIdx.x >> 5;  // 32 x 8
#pragma unroll
  for (int i = 0; i < 32; i += 8)
    tile[ty + i][tx] = f2bf(in[(size_t)(r0 + ty + i) * C + c0 + tx]);
  __syncthreads();
#pragma unroll
  for (int i = 0; i < 32; i += 8)
    out[(size_t)(c0 + ty + i) * R + r0 + tx] = tile[tx][ty + i];
}

// ---------------- V[B,S,Kvh,H] -> Vt[B,Kvh,H,S] (bf16) ---------------------
__global__ __launch_bounds__(256) void k_transpose_v(const u16* __restrict__ in,
                                                     u16* __restrict__ out) {
  __shared__ u16 tile[32][33];
  int bkh = blockIdx.z;
  int b = bkh >> 2, kh = bkh & 3;
  int h0 = blockIdx.x * 32, s0 = blockIdx.y * 32;
  int tx = threadIdx.x & 31, ty = threadIdx.x >> 5;
  const u16* ib = in + (size_t)b * Sd * (Kvh * Hd) + kh * Hd;  // [s][h], stride Kvh*Hd
  u16* ob = out + (size_t)(b * Kvh + kh) * Hd * Sd;            // [h][s], stride Sd
#pragma unroll
  for (int i = 0; i < 32; i += 8)
    tile[ty + i][tx] = ib[(size_t)(s0 + ty + i) * (Kvh * Hd) + h0 + tx];
  __syncthreads();
#pragma unroll
  for (int i = 0; i < 32; i += 8)
    ob[(size_t)(h0 + ty + i) * Sd + s0 + tx] = tile[tx][ty + i];
}

// ---------------- RoPE cos/sin tables [B*L, 64] ----------------------------
__global__ __launch_bounds__(256) void k_rope_tables(const int* __restrict__ pos,
                                                     float* __restrict__ cosT,
                                                     float* __restrict__ sinT, int total) {
  int idx = blockIdx.x * 256 + threadIdx.x;
  if (idx >= total) return;
  int i = idx & 63, bt = idx >> 6;
  float p = (float)pos[bt];
  float ts = powf(10000.0f, (float)i * (1.0f / 64.0f));
  float x = p / ts;
  cosT[idx] = cosf(x);
  sinT[idx] = sinf(x);
}

// ---------------- RoPE on f32 Q, in place ----------------------------------
__global__ __launch_bounds__(256) void k_rope_q(float* __restrict__ x,
                                                const float* __restrict__ cosT,
                                                const float* __restrict__ sinT, int total) {
  int idx = blockIdx.x * 256 + threadIdx.x;
  if (idx >= total) return;
  int i = idx & 63;
  int nh = (idx >> 6) % Nh;
  int bt = idx / (64 * Nh);
  size_t base = ((size_t)bt * Nh + nh) * Hd;
  float c = cosT[bt * 64 + i], s = sinT[bt * 64 + i];
  float x1 = x[base + i], x2 = x[base + 64 + i];
  x[base + i]      = x1 * c - x2 * s;
  x[base + 64 + i] = x2 * c + x1 * s;
}

// ------- RoPE on f32 K [B,S,Kvh,H] -> bf16 out [B,Kvh,S,H] (one rounding) --
__global__ __launch_bounds__(256) void k_rope_k(const float* __restrict__ x,
                                                u16* __restrict__ out,
                                                const float* __restrict__ cosT,
                                                const float* __restrict__ sinT, int total) {
  int idx = blockIdx.x * 256 + threadIdx.x;
  if (idx >= total) return;
  int i = idx & 63;
  int kh = (idx >> 6) % Kvh;
  int bt = idx / (64 * Kvh);
  int b = bt >> 11, s = bt & 2047;
  size_t bi = ((size_t)bt * Kvh + kh) * Hd;
  size_t bo = (((size_t)b * Kvh + kh) * Sd + s) * Hd;
  float c = cosT[bt * 64 + i], sn = sinT[bt * 64 + i];
  float x1 = x[bi + i], x2 = x[bi + 64 + i];
  out[bo + i]      = f2bf(x1 * c - x2 * sn);
  out[bo + 64 + i] = f2bf(x2 * c + x1 * sn);
}

// ---------------- GEMM  C[M,N] = A[M,K] * Bt[N,K]^T  (m97 structure) -------
template <int OUT_F32>
__global__ __launch_bounds__(256) void k_gemm_bt(const u16* __restrict__ A,
                                                 const u16* __restrict__ Bt,
                                                 void* __restrict__ C,
                                                 int M, int Ncols, int Kd) {
  __shared__ u16 lA[128 * 32];
  __shared__ u16 lB[128 * 32];
  int tiles_n = Ncols >> 7;
  int bm = blockIdx.x / tiles_n, bn = blockIdx.x % tiles_n;
  int tid = threadIdx.x;
  int lane = tid & 63, wave = tid >> 6;
  int wr = wave >> 1, wc = wave & 1;
  int e0 = tid * 8;
  int r0 = e0 >> 5, c0 = e0 & 31;
  int lr = lane & 15, hi = lane >> 4;
  int kq = hi * 8;

  const u16* gA = A + (size_t)(bm * 128 + r0) * Kd + c0;
  const u16* gB = Bt + (size_t)(bn * 128 + r0) * Kd + c0;

  f32x4 acc[4][4] = {};

  for (int k0 = 0; k0 < Kd; k0 += 32) {
    __syncthreads();
    __builtin_amdgcn_global_load_lds(
        (const __attribute__((address_space(1))) uint32_t*)(gA + k0),
        (__attribute__((address_space(3))) uint32_t*)&lA[e0], 16, 0, 0);
    __builtin_amdgcn_global_load_lds(
        (const __attribute__((address_space(1))) uint32_t*)(gA + k0 + (size_t)64 * Kd),
        (__attribute__((address_space(3))) uint32_t*)&lA[e0 + 64 * 32], 16, 0, 0);
    __builtin_amdgcn_global_load_lds(
        (const __attribute__((address_space(1))) uint32_t*)(gB + k0),
        (__attribute__((address_space(3))) uint32_t*)&lB[e0], 16, 0, 0);
    __builtin_amdgcn_global_load_lds(
        (const __attribute__((address_space(1))) uint32_t*)(gB + k0 + (size_t)64 * Kd),
        (__attribute__((address_space(3))) uint32_t*)&lB[e0 + 64 * 32], 16, 0, 0);
    __syncthreads();

    bf16x8 af[4], bfr[4];
#pragma unroll
    for (int m = 0; m < 4; ++m)
      af[m] = *(const bf16x8*)&lA[(wr * 64 + m * 16 + lr) * 32 + kq];
#pragma unroll
    for (int n = 0; n < 4; ++n)
      bfr[n] = *(const bf16x8*)&lB[(wc * 64 + n * 16 + lr) * 32 + kq];
#pragma unroll
    for (int m = 0; m < 4; ++m)
#pragma unroll
      for (int n = 0; n < 4; ++n)
        acc[m][n] = __builtin_amdgcn_mfma_f32_16x16x32_bf16(af[m], bfr[n], acc[m][n], 0, 0, 0);
  }

  int orow0 = bm * 128 + wr * 64 + hi * 4;
  int ocol0 = bn * 128 + wc * 64 + lr;
#pragma unroll
  for (int m = 0; m < 4; ++m)
#pragma unroll
    for (int n = 0; n < 4; ++n)
#pragma unroll
      for (int q = 0; q < 4; ++q) {
        size_t idx = (size_t)(orow0 + m * 16 + q) * Ncols + ocol0 + n * 16;
        if (OUT_F32) ((float*)C)[idx] = acc[m][n][q];
        else         ((u16*)C)[idx]   = f2bf(acc[m][n][q]);
      }
}

// ---------------- merged K/V projection GEMM -------------------------------
// A[4096,2048] * BtKV[1024,2048]^T; cols 0..511 -> f32 Kf, 512..1023 -> bf16 Vb
__global__ __launch_bounds__(256) void k_gemm_kv(const u16* __restrict__ A,
                                                 const u16* __restrict__ Bt,
                                                 float* __restrict__ Ck,
                                                 u16* __restrict__ Cv) {
  __shared__ u16 lA[128 * 32];
  __shared__ u16 lB[128 * 32];
  int bm = blockIdx.x >> 3, bn = blockIdx.x & 7;
  int tid = threadIdx.x;
  int lane = tid & 63, wave = tid >> 6;
  int wr = wave >> 1, wc = wave & 1;
  int e0 = tid * 8;
  int r0 = e0 >> 5, c0 = e0 & 31;
  int lr = lane & 15, hi = lane >> 4;
  int kq = hi * 8;

  const u16* gA = A + (size_t)(bm * 128 + r0) * Dd + c0;
  const u16* gB = Bt + (size_t)(bn * 128 + r0) * Dd + c0;

  f32x4 acc[4][4] = {};

  for (int k0 = 0; k0 < Dd; k0 += 32) {
    __syncthreads();
    __builtin_amdgcn_global_load_lds(
        (const __attribute__((address_space(1))) uint32_t*)(gA + k0),
        (__attribute__((address_space(3))) uint32_t*)&lA[e0], 16, 0, 0);
    __builtin_amdgcn_global_load_lds(
        (const __attribute__((address_space(1))) uint32_t*)(gA + k0 + (size_t)64 * Dd),
        (__attribute__((address_space(3))) uint32_t*)&lA[e0 + 64 * 32], 16, 0, 0);
    __builtin_amdgcn_global_load_lds(
        (const __attribute__((address_space(1))) uint32_t*)(gB + k0),
        (__attribute__((address_space(3))) uint32_t*)&lB[e0], 16, 0, 0);
    __builtin_amdgcn_global_load_lds(
        (const __attribute__((address_space(1))) uint32_t*)(gB + k0 + (size_t)64 * Dd),
        (__attribute__((address_space(3))) uint32_t*)&lB[e0 + 64 * 32], 16, 0, 0);
    __syncthreads();

    bf16x8 af[4], bfr[4];
#pragma unroll
    for (int m = 0; m < 4; ++m)
      af[m] = *(const bf16x8*)&lA[(wr * 64 + m * 16 + lr) * 32 + kq];
#pragma unroll
    for (int n = 0; n < 4; ++n)
      bfr[n] = *(const bf16x8*)&lB[(wc * 64 + n * 16 + lr) * 32 + kq];
#pragma unroll
    for (int m = 0; m < 4; ++m)
#pragma unroll
      for (int n = 0; n < 4; ++n)
        acc[m][n] = __builtin_amdgcn_mfma_f32_16x16x32_bf16(af[m], bfr[n], acc[m][n], 0, 0, 0);
  }

  int orow0 = bm * 128 + wr * 64 + hi * 4;
  int ocol0 = bn * 128 + wc * 64 + lr;
  if (bn < 4) {  // K half -> f32
#pragma unroll
    for (int m = 0; m < 4; ++m)
#pragma unroll
      for (int n = 0; n < 4; ++n)
#pragma unroll
        for (int q = 0; q < 4; ++q)
          Ck[(size_t)(orow0 + m * 16 + q) * 512 + ocol0 + n * 16] = acc[m][n][q];
  } else {       // V half -> bf16
#pragma unroll
    for (int m = 0; m < 4; ++m)
#pragma unroll
      for (int n = 0; n < 4; ++n)
#pragma unroll
        for (int q = 0; q < 4; ++q)
          Cv[(size_t)(orow0 + m * 16 + q) * 512 + (ocol0 - 512) + n * 16] = f2bf(acc[m][n][q]);
  }
}

// ---------------- causal GQA flash attention (v5: interleaved q-tile pair) -
// 4 waves x 16 q-rows; block owns tiles {p, 31-p} and processes BOTH inside
// one shared K/V s-loop: stage rounds drop 33 -> 32-p (avg -26%), compute per
// barrier window doubles (96 MFMA). Double-buffered LDS staging (R3-proven),
// XCD chunk swizzle, T13 defer-max. No min-wave launch_bounds (R4 lesson).
__global__ __launch_bounds__(256) void k_attn(const float* __restrict__ Qf,
                                              const u16* __restrict__ K,   // [B][Kvh][S][H]
                                              const u16* __restrict__ Vt,  // [B][Kvh][H][S]
                                              u16* __restrict__ O) {
  __shared__ u16 kv[2][16384];   // per buf: K tile 64x128 (16KB) | V tile 128x64 (16KB)
  __shared__ u16 Pl[4][1024];    // per-wave P [16][64] bf16, swizzled

  int bid0 = blockIdx.x;                       // 512 blocks, 8 chunks of 64
  int bid = (bid0 & 7) * 64 + (bid0 >> 3);     // chunk c on XCD c: one (b,kh)
  int p = bid & 15, n = (bid >> 4) & 15, b = bid >> 8;
  int kh = n >> 2;  // G = 4
  int tid = threadIdx.x;
  int lane = tid & 63, wave = tid >> 6;
  int lr = lane & 15, hi = lane >> 4;
  int kq = hi * 8;

  const u16* Kbase = K + ((size_t)(b * Kvh + kh)) * Sd * Hd;   // row stride 256B
  const u16* Vbase = Vt + ((size_t)(b * Kvh + kh)) * Hd * Sd;  // row stride 4096B
  u16* Pw = &Pl[wave][0];

  int tA = p, tB = 31 - p;                 // small / big q-tile
  int t0A = tA * 64 + wave * 16;
  int t0B = tB * 64 + wave * 16;
  int nstA = tA + 1, nstB = tB + 1;        // nstB >= 17 > nstA always

  // ---- Q fragments for both tiles, hi/lo split from f32 ----
  bf16x8 qhA[4], qlA[4], qhB[4], qlB[4];
  {
    const float* qrowA = Qf + ((size_t)((b * Td + t0A + lr) * Nh + n)) * Hd;
    const float* qrowB = Qf + ((size_t)((b * Td + t0B + lr) * Nh + n)) * Hd;
#pragma unroll
    for (int kk = 0; kk < 4; ++kk) {
#pragma unroll
      for (int jj = 0; jj < 8; ++jj) {
        float xa = qrowA[kk * 32 + kq + jj];
        u16 ha = f2bf(xa);
        qhA[kk][jj] = (short)ha;
        qlA[kk][jj] = (short)f2bf(xa - bf2f(ha));
        float xb = qrowB[kk * 32 + kq + jj];
        u16 hb2 = f2bf(xb);
        qhB[kk][jj] = (short)hb2;
        qlB[kk][jj] = (short)f2bf(xb - bf2f(hb2));
      }
    }
  }

  float mA[4] = {-1e30f, -1e30f, -1e30f, -1e30f};
  float lA_[4] = {0.f, 0.f, 0.f, 0.f};
  f32x4 oA[8] = {};
  float mB[4] = {-1e30f, -1e30f, -1e30f, -1e30f};
  float lB_[4] = {0.f, 0.f, 0.f, 0.f};
  f32x4 oB[8] = {};

  // one q-tile's full update for one s-tile (inlined twice per iteration)
  auto DO_TILE = [&](int t0, bf16x8 (&qh)[4], bf16x8 (&ql)[4],
                     float (&m_run)[4], float (&l_run)[4], f32x4 (&oacc)[8],
                     int s0, const char* kb) {
    f32x4 sc[4] = {};
#pragma unroll
    for (int j = 0; j < 4; ++j) {
      int r = j * 16 + lr;
      int rx = (r & 7) << 4;
#pragma unroll
      for (int kk = 0; kk < 4; ++kk) {
        bf16x8 kf = *(const bf16x8*)(kb + r * 256 + ((kk * 64 + hi * 16) ^ rx));
        sc[j] = __builtin_amdgcn_mfma_f32_16x16x32_bf16(qh[kk], kf, sc[j], 0, 0, 0);
        sc[j] = __builtin_amdgcn_mfma_f32_16x16x32_bf16(ql[kk], kf, sc[j], 0, 0, 0);
      }
    }
    if (s0 + 63 > t0) {
#pragma unroll
      for (int j = 0; j < 4; ++j) {
        if (s0 + j * 16 + 15 > t0) {
          int s = s0 + j * 16 + lr;
#pragma unroll
          for (int q = 0; q < 4; ++q)
            if (s > t0 + hi * 4 + q) sc[j][q] = -1e30f;
        }
      }
    }
    float mb[4], ls[4];
#pragma unroll
    for (int q = 0; q < 4; ++q)
      mb[q] = fmaxf(fmaxf(sc[0][q], sc[1][q]), fmaxf(sc[2][q], sc[3][q]));
#pragma unroll
    for (int off = 1; off < 16; off <<= 1) {
#pragma unroll
      for (int q = 0; q < 4; ++q) mb[q] = fmaxf(mb[q], __shfl_xor(mb[q], off));
    }
    bool need = (mb[0] > m_run[0] + 8.f) || (mb[1] > m_run[1] + 8.f) ||
                (mb[2] > m_run[2] + 8.f) || (mb[3] > m_run[3] + 8.f);
    if (__any(need)) {
      float fac[4];
#pragma unroll
      for (int q = 0; q < 4; ++q) {
        float mn = fmaxf(m_run[q], mb[q]);
        fac[q] = __expf(m_run[q] - mn);
        m_run[q] = mn;
        l_run[q] *= fac[q];
      }
#pragma unroll
      for (int hb = 0; hb < 8; ++hb)
#pragma unroll
        for (int q = 0; q < 4; ++q) oacc[hb][q] *= fac[q];
    }
#pragma unroll
    for (int j = 0; j < 4; ++j)
#pragma unroll
      for (int q = 0; q < 4; ++q) sc[j][q] = __expf(sc[j][q] - m_run[q]);
#pragma unroll
    for (int q = 0; q < 4; ++q)
      ls[q] = (sc[0][q] + sc[1][q]) + (sc[2][q] + sc[3][q]);
#pragma unroll
    for (int off = 1; off < 16; off <<= 1) {
#pragma unroll
      for (int q = 0; q < 4; ++q) ls[q] += __shfl_xor(ls[q], off);
    }
#pragma unroll
    for (int q = 0; q < 4; ++q) l_run[q] += ls[q];

    // P: C-layout -> bf16 A-layout via per-wave swizzled LDS
#pragma unroll
    for (int j = 0; j < 4; ++j)
#pragma unroll
      for (int q = 0; q < 4; ++q) {
        int row = hi * 4 + q;
        int cb = ((j * 16 + lr) * 2) ^ ((row & 7) << 4);
        *(u16*)((char*)Pw + row * 128 + cb) = f2bf(sc[j][q]);
      }
    bf16x8 pf[2];
    {
      int rx = (lr & 7) << 4;
#pragma unroll
      for (int c = 0; c < 2; ++c)
        pf[c] = *(const bf16x8*)((const char*)Pw + lr * 128 + ((c * 64 + hi * 16) ^ rx));
    }
#pragma unroll
    for (int hb = 0; hb < 8; ++hb) {
      int h = hb * 16 + lr;
      int rx = (h & 7) << 4;
#pragma unroll
      for (int c = 0; c < 2; ++c) {
        bf16x8 vf = *(const bf16x8*)(kb + 16384 + h * 128 + ((c * 64 + hi * 16) ^ rx));
        oacc[hb] = __builtin_amdgcn_mfma_f32_16x16x32_bf16(pf[c], vf, oacc[hb], 0, 0, 0);
      }
    }
  };

  // stage s-tile st into kv[buf]: LDS linear, global source pre-swizzled
  auto STAGE = [&](int st, int buf) {
    int s0 = st * 64;
    char* kb = (char*)&kv[buf][0];
#pragma unroll
    for (int it = 0; it < 4; ++it) {  // K: 16KB
      int o = it * 4096 + tid * 16;
      int r = o >> 8, w = o & 255;
      const u16* src = Kbase + (size_t)(s0 + r) * Hd + ((w ^ ((r & 7) << 4)) >> 1);
      __builtin_amdgcn_global_load_lds(
          (const __attribute__((address_space(1))) uint32_t*)src,
          (__attribute__((address_space(3))) uint32_t*)(kb + o), 16, 0, 0);
    }
#pragma unroll
    for (int it = 0; it < 4; ++it) {  // V: 16KB
      int o = it * 4096 + tid * 16;
      int h = o >> 7, w = o & 127;
      const u16* src = Vbase + (size_t)h * Sd + s0 + ((w ^ ((h & 7) << 4)) >> 1);
      __builtin_amdgcn_global_load_lds(
          (const __attribute__((address_space(1))) uint32_t*)src,
          (__attribute__((address_space(3))) uint32_t*)(kb + 16384 + o), 16, 0, 0);
    }
  };

  int cur = 0;
  STAGE(0, 0);
  asm volatile("s_waitcnt vmcnt(0)" ::: "memory");
  __syncthreads();

  for (int st = 0; st < nstB; ++st) {
    if (st + 1 < nstB) STAGE(st + 1, cur ^ 1);
    int s0 = st * 64;
    const char* kb = (const char*)&kv[cur][0];

    DO_TILE(t0B, qhB, qlB, mB, lB_, oB, s0, kb);
    if (st < nstA) DO_TILE(t0A, qhA, qlA, mA, lA_, oA, s0, kb);

    asm volatile("s_waitcnt vmcnt(0)" ::: "memory");
    __syncthreads();
    cur ^= 1;
  }

  // ---- epilogue: normalize + store both tiles ----
#pragma unroll
  for (int hb = 0; hb < 8; ++hb)
#pragma unroll
    for (int q = 0; q < 4; ++q) {
      float vB = oB[hb][q] / lB_[q];
      O[((size_t)((b * Td + t0B + hi * 4 + q) * Nh + n)) * Hd + hb * 16 + lr] = f2bf(vB);
      float vA = oA[hb][q] / lA_[q];
      O[((size_t)((b * Td + t0A + hi * 4 + q) * Nh + n)) * Hd + hb * 16 + lr] = f2bf(vA);
    }
}

// ---------------------------------------------------------------------------
extern "C" void kernel_launch(void* const* d_in, const int* in_sizes, int n_in,
                              void* d_out, int out_size, void* d_ws, size_t ws_size,
                              hipStream_t stream) {
  (void)in_sizes; (void)n_in; (void)out_size; (void)ws_size;
  const float* Xq  = (const float*)d_in[0];
  const float* Xkv = (const float*)d_in[1];
  const int* qpos  = (const int*)d_in[2];
  const int* kpos  = (const int*)d_in[3];
  const float* Wq  = (const float*)d_in[4];
  const float* Wk  = (const float*)d_in[5];
  const float* Wv  = (const float*)d_in[6];
  const float* Wo  = (const float*)d_in[7];
  float* out = (float*)d_out;

  char* ws = (char*)d_ws;
  size_t off = 0;
  auto take = [&](size_t bytes) -> char* {
    char* p = ws + off;
    off += (bytes + 255) & ~(size_t)255;
    return p;
  };
  const size_t nX   = (size_t)Bb * Td * Dd;        // 8,388,608
  const size_t nQ   = (size_t)Bb * Td * Nh * Hd;   // 8,388,608
  const size_t nKV  = (size_t)Bb * Sd * Kvh * Hd;  // 2,097,152
  const size_t nTab = (size_t)Bb * Td * 64;        // 262,144

  u16* XqB   = (u16*)take(nX * 2);                     // reused: Kf, attn out
  u16* XkvB  = (u16*)take(nX * 2);                     // reused as Vt
  u16* WqT   = (u16*)take((size_t)Nh * Hd * Dd * 2);
  u16* BtKV  = (u16*)take((size_t)(Kvh * Hd * 2) * Dd * 2);  // [1024][2048]
  u16* WoT   = (u16*)take((size_t)Dd * Nh * Hd * 2);
  float* Qf  = (float*)take(nQ * 4);                   // f32 Q (RoPE in f32)
  u16* Kb    = (u16*)take(nKV * 2);                    // [B][Kvh][S][H]
  u16* Vb    = (u16*)take(nKV * 2);
  float* cosQ = (float*)take(nTab * 4);
  float* sinQ = (float*)take(nTab * 4);
  float* cosK = (float*)take(nTab * 4);
  float* sinK = (float*)take(nTab * 4);
  // Aliases (lifetimes sequenced):
  float* Kf  = (float*)XqB;  // f32 K proj out; written after Q-proj reads XqB; dead after k_rope_k
  u16* attnB = XqB;          // attn output; written after Kf dead
  u16* Vt    = XkvB;         // XkvB dead after KV-proj

  k_convert<<<dim3((int)(nX / 8 / 256)), 256, 0, stream>>>(Xq, XqB, (int)(nX / 8));
  k_convert<<<dim3((int)(nX / 8 / 256)), 256, 0, stream>>>(Xkv, XkvB, (int)(nX / 8));
  k_transpose_f32_bf16<<<dim3((Nh * Hd) / 32, Dd / 32), 256, 0, stream>>>(Wq, WqT, Dd, Nh * Hd);
  k_transpose_f32_bf16<<<dim3((Kvh * Hd) / 32, Dd / 32), 256, 0, stream>>>(Wk, BtKV, Dd, Kvh * Hd);
  k_transpose_f32_bf16<<<dim3((Kvh * Hd) / 32, Dd / 32), 256, 0, stream>>>(
      Wv, BtKV + (size_t)512 * Dd, Dd, Kvh * Hd);
  k_transpose_f32_bf16<<<dim3(Dd / 32, (Nh * Hd) / 32), 256, 0, stream>>>(Wo, WoT, Nh * Hd, Dd);
  k_rope_tables<<<dim3((int)(nTab / 256)), 256, 0, stream>>>(qpos, cosQ, sinQ, (int)nTab);
  k_rope_tables<<<dim3((int)(nTab / 256)), 256, 0, stream>>>(kpos, cosK, sinK, (int)nTab);

  // Q projection -> f32
  k_gemm_bt<1><<<dim3((Bb * Td / 128) * ((Nh * Hd) / 128)), 256, 0, stream>>>(
      XqB, WqT, Qf, Bb * Td, Nh * Hd, Dd);
  // merged K (f32) + V (bf16) projection
  k_gemm_kv<<<dim3((Bb * Td / 128) * 8), 256, 0, stream>>>(XkvB, BtKV, Kf, Vb);

  k_rope_q<<<dim3(Bb * Td * Nh * 64 / 256), 256, 0, stream>>>(
      Qf, cosQ, sinQ, Bb * Td * Nh * 64);
  k_rope_k<<<dim3(Bb * Sd * Kvh * 64 / 256), 256, 0, stream>>>(
      Kf, Kb, cosK, sinK, Bb * Sd * Kvh * 64);
  k_transpose_v<<<dim3(Hd / 32, Sd / 32, Bb * Kvh), 256, 0, stream>>>(Vb, Vt);

  k_attn<<<dim3(Bb * Nh * 16), 256, 0, stream>>>(Qf, Kb, Vt, attnB);

  k_gemm_bt<1><<<dim3((Bb * Td / 128) * ((Nh * Hd) / 128)), 256, 0, stream>>>(
      attnB, WoT, out, Bb * Td, Nh * Hd, Dd);
}

// Round 7
// 292.473 us; speedup vs baseline: 1.3140x; 1.3140x over previous
//
#include <hip/hip_runtime.h>
#include <stdint.h>

#define Bb 2
#define Td 2048
#define Sd 2048
#define Dd 2048
#define Nh 16
#define Kvh 4
#define Hd 128
// G = Nh/Kvh = 4

typedef unsigned short u16;
typedef short bf16x8 __attribute__((ext_vector_type(8)));
typedef float f32x4 __attribute__((ext_vector_type(4)));

__device__ __forceinline__ u16 f2bf(float f) {
  union { float f; unsigned u; } v; v.f = f;
  v.u += 0x7FFF + ((v.u >> 16) & 1);   // round-to-nearest-even
  return (u16)(v.u >> 16);
}
__device__ __forceinline__ float bf2f(u16 h) {
  union { unsigned u; float f; } v; v.u = ((unsigned)h) << 16;
  return v.f;
}

// ---------------- f32 -> bf16 bulk convert (8 elems/thread, 16B stores) ----
__global__ __launch_bounds__(256) void k_convert(const float* __restrict__ in,
                                                 u16* __restrict__ out, int n8) {
  int i = blockIdx.x * 256 + threadIdx.x;
  if (i >= n8) return;
  const float4* p = (const float4*)in;
  float4 a = p[(size_t)i * 2], b = p[(size_t)i * 2 + 1];
  ushort4 r0, r1;
  r0.x = f2bf(a.x); r0.y = f2bf(a.y); r0.z = f2bf(a.z); r0.w = f2bf(a.w);
  r1.x = f2bf(b.x); r1.y = f2bf(b.y); r1.z = f2bf(b.z); r1.w = f2bf(b.w);
  ((ushort4*)out)[(size_t)i * 2] = r0;
  ((ushort4*)out)[(size_t)i * 2 + 1] = r1;
}

// ---------------- tiled transpose f32[R,C] -> bf16[C,R] --------------------
__global__ __launch_bounds__(256) void k_transpose_f32_bf16(const float* __restrict__ in,
                                                            u16* __restrict__ out,
                                                            int R, int C) {
  __shared__ u16 tile[32][33];
  int c0 = blockIdx.x * 32, r0 = blockIdx.y * 32;
  int tx = threadIdx.x & 31, ty = threadIdx.x >> 5;  // 32 x 8
#pragma unroll
  for (int i = 0; i < 32; i += 8)
    tile[ty + i][tx] = f2bf(in[(size_t)(r0 + ty + i) * C + c0 + tx]);
  __syncthreads();
#pragma unroll
  for (int i = 0; i < 32; i += 8)
    out[(size_t)(c0 + ty + i) * R + r0 + tx] = tile[tx][ty + i];
}

// ---------------- V[B,S,Kvh,H] -> Vt[B,Kvh,H,S] (bf16) ---------------------
__global__ __launch_bounds__(256) void k_transpose_v(const u16* __restrict__ in,
                                                     u16* __restrict__ out) {
  __shared__ u16 tile[32][33];
  int bkh = blockIdx.z;
  int b = bkh >> 2, kh = bkh & 3;
  int h0 = blockIdx.x * 32, s0 = blockIdx.y * 32;
  int tx = threadIdx.x & 31, ty = threadIdx.x >> 5;
  const u16* ib = in + (size_t)b * Sd * (Kvh * Hd) + kh * Hd;  // [s][h], stride Kvh*Hd
  u16* ob = out + (size_t)(b * Kvh + kh) * Hd * Sd;            // [h][s], stride Sd
#pragma unroll
  for (int i = 0; i < 32; i += 8)
    tile[ty + i][tx] = ib[(size_t)(s0 + ty + i) * (Kvh * Hd) + h0 + tx];
  __syncthreads();
#pragma unroll
  for (int i = 0; i < 32; i += 8)
    ob[(size_t)(h0 + ty + i) * Sd + s0 + tx] = tile[tx][ty + i];
}

// ---------------- RoPE cos/sin tables [B*L, 64] ----------------------------
__global__ __launch_bounds__(256) void k_rope_tables(const int* __restrict__ pos,
                                                     float* __restrict__ cosT,
                                                     float* __restrict__ sinT, int total) {
  int idx = blockIdx.x * 256 + threadIdx.x;
  if (idx >= total) return;
  int i = idx & 63, bt = idx >> 6;
  float p = (float)pos[bt];
  float ts = powf(10000.0f, (float)i * (1.0f / 64.0f));
  float x = p / ts;
  cosT[idx] = cosf(x);
  sinT[idx] = sinf(x);
}

// ---- Q projection + fused RoPE -> f32 Qf[B*T, Nh*Hd] ----------------------
// Column remap: wave wc owns cols {wc*32..+31} and {64+wc*32..+31} of the
// 128-wide head (one head per bn block), so RoPE pair (i, i+64) is in-wave:
// acc[m][n] (n<2) pairs with acc[m][n+2]. RoPE applied in f32 registers.
__global__ __launch_bounds__(256) void k_gemm_q(const u16* __restrict__ A,
                                                const u16* __restrict__ Bt,
                                                float* __restrict__ Cq,
                                                const float* __restrict__ cosT,
                                                const float* __restrict__ sinT) {
  __shared__ u16 lA[128 * 32];
  __shared__ u16 lB[128 * 32];
  int tiles_n = (Nh * Hd) >> 7;  // 16
  int bm = blockIdx.x / tiles_n, bn = blockIdx.x % tiles_n;
  int tid = threadIdx.x;
  int lane = tid & 63, wave = tid >> 6;
  int wr = wave >> 1, wc = wave & 1;
  int e0 = tid * 8;
  int r0 = e0 >> 5, c0 = e0 & 31;
  int lr = lane & 15, hi = lane >> 4;
  int kq = hi * 8;

  const u16* gA = A + (size_t)(bm * 128 + r0) * Dd + c0;
  const u16* gB = Bt + (size_t)(bn * 128 + r0) * Dd + c0;

  f32x4 acc[4][4] = {};

  for (int k0 = 0; k0 < Dd; k0 += 32) {
    __syncthreads();
    __builtin_amdgcn_global_load_lds(
        (const __attribute__((address_space(1))) uint32_t*)(gA + k0),
        (__attribute__((address_space(3))) uint32_t*)&lA[e0], 16, 0, 0);
    __builtin_amdgcn_global_load_lds(
        (const __attribute__((address_space(1))) uint32_t*)(gA + k0 + (size_t)64 * Dd),
        (__attribute__((address_space(3))) uint32_t*)&lA[e0 + 64 * 32], 16, 0, 0);
    __builtin_amdgcn_global_load_lds(
        (const __attribute__((address_space(1))) uint32_t*)(gB + k0),
        (__attribute__((address_space(3))) uint32_t*)&lB[e0], 16, 0, 0);
    __builtin_amdgcn_global_load_lds(
        (const __attribute__((address_space(1))) uint32_t*)(gB + k0 + (size_t)64 * Dd),
        (__attribute__((address_space(3))) uint32_t*)&lB[e0 + 64 * 32], 16, 0, 0);
    __syncthreads();

    bf16x8 af[4], bfr[4];
#pragma unroll
    for (int m = 0; m < 4; ++m)
      af[m] = *(const bf16x8*)&lA[(wr * 64 + m * 16 + lr) * 32 + kq];
#pragma unroll
    for (int n = 0; n < 4; ++n) {
      int rB = (n >> 1) * 64 + wc * 32 + (n & 1) * 16 + lr;  // remapped col row
      bfr[n] = *(const bf16x8*)&lB[rB * 32 + kq];
    }
#pragma unroll
    for (int m = 0; m < 4; ++m)
#pragma unroll
      for (int n = 0; n < 4; ++n)
        acc[m][n] = __builtin_amdgcn_mfma_f32_16x16x32_bf16(af[m], bfr[n], acc[m][n], 0, 0, 0);
  }

  int orow0 = bm * 128 + wr * 64 + hi * 4;
  int head = bn;
#pragma unroll
  for (int m = 0; m < 4; ++m)
#pragma unroll
    for (int n = 0; n < 2; ++n) {
      int i = wc * 32 + n * 16 + lr;   // 0..63 within head
#pragma unroll
      for (int q = 0; q < 4; ++q) {
        int r = orow0 + m * 16 + q;
        float c = cosT[r * 64 + i], s = sinT[r * 64 + i];
        float x1 = acc[m][n][q], x2 = acc[m][n + 2][q];
        size_t base = (size_t)r * (Nh * Hd) + head * Hd;
        Cq[base + i]      = x1 * c - x2 * s;
        Cq[base + i + 64] = x2 * c + x1 * s;
      }
    }
}

// ---- merged K/V projection + fused RoPE-K ---------------------------------
// A[4096,2048] * BtKV[1024,2048]^T with remapped columns.
// bn<4: K head bn -> RoPE f32 -> bf16 Kb[B][Kvh][S][H] (single rounding).
// bn>=4: V -> bf16 Vb[B*S, 512].
__global__ __launch_bounds__(256) void k_gemm_kv(const u16* __restrict__ A,
                                                 const u16* __restrict__ Bt,
                                                 u16* __restrict__ Kb,
                                                 u16* __restrict__ Cv,
                                                 const float* __restrict__ cosT,
                                                 const float* __restrict__ sinT) {
  __shared__ u16 lA[128 * 32];
  __shared__ u16 lB[128 * 32];
  int bm = blockIdx.x >> 3, bn = blockIdx.x & 7;
  int tid = threadIdx.x;
  int lane = tid & 63, wave = tid >> 6;
  int wr = wave >> 1, wc = wave & 1;
  int e0 = tid * 8;
  int r0 = e0 >> 5, c0 = e0 & 31;
  int lr = lane & 15, hi = lane >> 4;
  int kq = hi * 8;

  const u16* gA = A + (size_t)(bm * 128 + r0) * Dd + c0;
  const u16* gB = Bt + (size_t)(bn * 128 + r0) * Dd + c0;

  f32x4 acc[4][4] = {};

  for (int k0 = 0; k0 < Dd; k0 += 32) {
    __syncthreads();
    __builtin_amdgcn_global_load_lds(
        (const __attribute__((address_space(1))) uint32_t*)(gA + k0),
        (__attribute__((address_space(3))) uint32_t*)&lA[e0], 16, 0, 0);
    __builtin_amdgcn_global_load_lds(
        (const __attribute__((address_space(1))) uint32_t*)(gA + k0 + (size_t)64 * Dd),
        (__attribute__((address_space(3))) uint32_t*)&lA[e0 + 64 * 32], 16, 0, 0);
    __builtin_amdgcn_global_load_lds(
        (const __attribute__((address_space(1))) uint32_t*)(gB + k0),
        (__attribute__((address_space(3))) uint32_t*)&lB[e0], 16, 0, 0);
    __builtin_amdgcn_global_load_lds(
        (const __attribute__((address_space(1))) uint32_t*)(gB + k0 + (size_t)64 * Dd),
        (__attribute__((address_space(3))) uint32_t*)&lB[e0 + 64 * 32], 16, 0, 0);
    __syncthreads();

    bf16x8 af[4], bfr[4];
#pragma unroll
    for (int m = 0; m < 4; ++m)
      af[m] = *(const bf16x8*)&lA[(wr * 64 + m * 16 + lr) * 32 + kq];
#pragma unroll
    for (int n = 0; n < 4; ++n) {
      int rB = (n >> 1) * 64 + wc * 32 + (n & 1) * 16 + lr;
      bfr[n] = *(const bf16x8*)&lB[rB * 32 + kq];
    }
#pragma unroll
    for (int m = 0; m < 4; ++m)
#pragma unroll
      for (int n = 0; n < 4; ++n)
        acc[m][n] = __builtin_amdgcn_mfma_f32_16x16x32_bf16(af[m], bfr[n], acc[m][n], 0, 0, 0);
  }

  int orow0 = bm * 128 + wr * 64 + hi * 4;
  if (bn < 4) {  // K head bn: RoPE + bf16, layout [B][Kvh][S][H]
    int kh = bn;
#pragma unroll
    for (int m = 0; m < 4; ++m)
#pragma unroll
      for (int n = 0; n < 2; ++n) {
        int i = wc * 32 + n * 16 + lr;
#pragma unroll
        for (int q = 0; q < 4; ++q) {
          int r = orow0 + m * 16 + q;
          int b = r >> 11, s = r & 2047;
          float c = cosT[r * 64 + i], sn = sinT[r * 64 + i];
          float x1 = acc[m][n][q], x2 = acc[m][n + 2][q];
          size_t base = (((size_t)(b * Kvh + kh)) * Sd + s) * Hd;
          Kb[base + i]      = f2bf(x1 * c - x2 * sn);
          Kb[base + i + 64] = f2bf(x2 * c + x1 * sn);
        }
      }
  } else {       // V half -> bf16 [B*S, 512]
#pragma unroll
    for (int m = 0; m < 4; ++m)
#pragma unroll
      for (int n = 0; n < 4; ++n) {
        int col = (bn - 4) * 128 + (n >> 1) * 64 + wc * 32 + (n & 1) * 16 + lr;
#pragma unroll
        for (int q = 0; q < 4; ++q)
          Cv[(size_t)(orow0 + m * 16 + q) * 512 + col] = f2bf(acc[m][n][q]);
      }
  }
}

// ---------------- GEMM  C[M,N] = A[M,K] * Bt[N,K]^T  (m97, o-proj) ---------
__global__ __launch_bounds__(256) void k_gemm_bt(const u16* __restrict__ A,
                                                 const u16* __restrict__ Bt,
                                                 float* __restrict__ C,
                                                 int M, int Ncols, int Kd) {
  __shared__ u16 lA[128 * 32];
  __shared__ u16 lB[128 * 32];
  int tiles_n = Ncols >> 7;
  int bm = blockIdx.x / tiles_n, bn = blockIdx.x % tiles_n;
  int tid = threadIdx.x;
  int lane = tid & 63, wave = tid >> 6;
  int wr = wave >> 1, wc = wave & 1;
  int e0 = tid * 8;
  int r0 = e0 >> 5, c0 = e0 & 31;
  int lr = lane & 15, hi = lane >> 4;
  int kq = hi * 8;

  const u16* gA = A + (size_t)(bm * 128 + r0) * Kd + c0;
  const u16* gB = Bt + (size_t)(bn * 128 + r0) * Kd + c0;

  f32x4 acc[4][4] = {};

  for (int k0 = 0; k0 < Kd; k0 += 32) {
    __syncthreads();
    __builtin_amdgcn_global_load_lds(
        (const __attribute__((address_space(1))) uint32_t*)(gA + k0),
        (__attribute__((address_space(3))) uint32_t*)&lA[e0], 16, 0, 0);
    __builtin_amdgcn_global_load_lds(
        (const __attribute__((address_space(1))) uint32_t*)(gA + k0 + (size_t)64 * Kd),
        (__attribute__((address_space(3))) uint32_t*)&lA[e0 + 64 * 32], 16, 0, 0);
    __builtin_amdgcn_global_load_lds(
        (const __attribute__((address_space(1))) uint32_t*)(gB + k0),
        (__attribute__((address_space(3))) uint32_t*)&lB[e0], 16, 0, 0);
    __builtin_amdgcn_global_load_lds(
        (const __attribute__((address_space(1))) uint32_t*)(gB + k0 + (size_t)64 * Kd),
        (__attribute__((address_space(3))) uint32_t*)&lB[e0 + 64 * 32], 16, 0, 0);
    __syncthreads();

    bf16x8 af[4], bfr[4];
#pragma unroll
    for (int m = 0; m < 4; ++m)
      af[m] = *(const bf16x8*)&lA[(wr * 64 + m * 16 + lr) * 32 + kq];
#pragma unroll
    for (int n = 0; n < 4; ++n)
      bfr[n] = *(const bf16x8*)&lB[(wc * 64 + n * 16 + lr) * 32 + kq];
#pragma unroll
    for (int m = 0; m < 4; ++m)
#pragma unroll
      for (int n = 0; n < 4; ++n)
        acc[m][n] = __builtin_amdgcn_mfma_f32_16x16x32_bf16(af[m], bfr[n], acc[m][n], 0, 0, 0);
  }

  int orow0 = bm * 128 + wr * 64 + hi * 4;
  int ocol0 = bn * 128 + wc * 64 + lr;
#pragma unroll
  for (int m = 0; m < 4; ++m)
#pragma unroll
    for (int n = 0; n < 4; ++n)
#pragma unroll
      for (int q = 0; q < 4; ++q)
        C[(size_t)(orow0 + m * 16 + q) * Ncols + ocol0 + n * 16] = acc[m][n][q];
}

// ---------------- causal GQA flash attention (R5-proven v4) ----------------
// 4 waves x 16 q-rows; paired tiles {p,31-p}; K/V double-buffered in LDS
// (KVBLK=64) via global_load_lds pre-swizzled source; XCD chunk swizzle;
// T13 defer-max. No min-wave launch_bounds (R4: forced 64 VGPR -> spills).
// R6 lesson: do NOT interleave the pair (2x live VGPR -> occupancy halves).
__global__ __launch_bounds__(256) void k_attn(const float* __restrict__ Qf,
                                              const u16* __restrict__ K,   // [B][Kvh][S][H]
                                              const u16* __restrict__ Vt,  // [B][Kvh][H][S]
                                              u16* __restrict__ O) {
  __shared__ u16 kv[2][16384];   // per buf: K tile 64x128 (16KB) | V tile 128x64 (16KB)
  __shared__ u16 Pl[4][1024];    // per-wave P [16][64] bf16, swizzled

  int bid0 = blockIdx.x;                       // 512 blocks, 8 chunks of 64
  int bid = (bid0 & 7) * 64 + (bid0 >> 3);     // chunk c on XCD c: one (b,kh)
  int p = bid & 15, n = (bid >> 4) & 15, b = bid >> 8;
  int kh = n >> 2;  // G = 4
  int tid = threadIdx.x;
  int lane = tid & 63, wave = tid >> 6;
  int lr = lane & 15, hi = lane >> 4;
  int kq = hi * 8;

  const u16* Kbase = K + ((size_t)(b * Kvh + kh)) * Sd * Hd;   // row stride 256B
  const u16* Vbase = Vt + ((size_t)(b * Kvh + kh)) * Hd * Sd;  // row stride 4096B
  u16* Pw = &Pl[wave][0];

  for (int half = 0; half < 2; ++half) {
    int tile = half ? (31 - p) : p;
    int t0 = tile * 64 + wave * 16;

    // ---- Q fragments, hi/lo split from f32 ----
    bf16x8 qhi[4], qlo[4];
    {
      const float* qrow = Qf + ((size_t)((b * Td + t0 + lr) * Nh + n)) * Hd;
#pragma unroll
      for (int kk = 0; kk < 4; ++kk) {
        float4 a = *(const float4*)(qrow + kk * 32 + kq);
        float4 c = *(const float4*)(qrow + kk * 32 + kq + 4);
        float xs[8] = {a.x, a.y, a.z, a.w, c.x, c.y, c.z, c.w};
#pragma unroll
        for (int jj = 0; jj < 8; ++jj) {
          u16 h = f2bf(xs[jj]);
          qhi[kk][jj] = (short)h;
          qlo[kk][jj] = (short)f2bf(xs[jj] - bf2f(h));
        }
      }
    }

    float m_run[4] = {-1e30f, -1e30f, -1e30f, -1e30f};
    float l_run[4] = {0.f, 0.f, 0.f, 0.f};
    f32x4 oacc[8] = {};

    int nst = tile + 1;  // number of 64-wide s-tiles

    // stage s-tile st into kv[buf]: LDS linear, global source pre-swizzled
    auto STAGE = [&](int st, int buf) {
      int s0 = st * 64;
      char* kb = (char*)&kv[buf][0];
#pragma unroll
      for (int it = 0; it < 4; ++it) {  // K: 16KB
        int o = it * 4096 + tid * 16;
        int r = o >> 8, w = o & 255;
        const u16* src = Kbase + (size_t)(s0 + r) * Hd + ((w ^ ((r & 7) << 4)) >> 1);
        __builtin_amdgcn_global_load_lds(
            (const __attribute__((address_space(1))) uint32_t*)src,
            (__attribute__((address_space(3))) uint32_t*)(kb + o), 16, 0, 0);
      }
#pragma unroll
      for (int it = 0; it < 4; ++it) {  // V: 16KB
        int o = it * 4096 + tid * 16;
        int h = o >> 7, w = o & 127;
        const u16* src = Vbase + (size_t)h * Sd + s0 + ((w ^ ((h & 7) << 4)) >> 1);
        __builtin_amdgcn_global_load_lds(
            (const __attribute__((address_space(1))) uint32_t*)src,
            (__attribute__((address_space(3))) uint32_t*)(kb + 16384 + o), 16, 0, 0);
      }
    };

    int cur = 0;
    STAGE(0, 0);
    asm volatile("s_waitcnt vmcnt(0)" ::: "memory");
    __syncthreads();

    for (int st = 0; st < nst; ++st) {
      if (st + 1 < nst) STAGE(st + 1, cur ^ 1);
      int s0 = st * 64;
      const char* kb = (const char*)&kv[cur][0];

      // ---- QK^T: 4 j-subtiles x 4 k-chunks x (hi+lo) ----
      f32x4 sc[4] = {};
#pragma unroll
      for (int j = 0; j < 4; ++j) {
        int r = j * 16 + lr;
        int rx = (r & 7) << 4;
#pragma unroll
        for (int kk = 0; kk < 4; ++kk) {
          bf16x8 kf = *(const bf16x8*)(kb + r * 256 + ((kk * 64 + hi * 16) ^ rx));
          sc[j] = __builtin_amdgcn_mfma_f32_16x16x32_bf16(qhi[kk], kf, sc[j], 0, 0, 0);
          sc[j] = __builtin_amdgcn_mfma_f32_16x16x32_bf16(qlo[kk], kf, sc[j], 0, 0, 0);
        }
      }

      // ---- causal mask ----
      if (s0 + 63 > t0) {
#pragma unroll
        for (int j = 0; j < 4; ++j) {
          if (s0 + j * 16 + 15 > t0) {
            int s = s0 + j * 16 + lr;
#pragma unroll
            for (int q = 0; q < 4; ++q)
              if (s > t0 + hi * 4 + q) sc[j][q] = -1e30f;
          }
        }
      }

      // ---- online softmax (T13 defer-max) ----
      float mb[4], ls[4];
#pragma unroll
      for (int q = 0; q < 4; ++q)
        mb[q] = fmaxf(fmaxf(sc[0][q], sc[1][q]), fmaxf(sc[2][q], sc[3][q]));
#pragma unroll
      for (int off = 1; off < 16; off <<= 1) {
#pragma unroll
        for (int q = 0; q < 4; ++q) mb[q] = fmaxf(mb[q], __shfl_xor(mb[q], off));
      }
      bool need = (mb[0] > m_run[0] + 8.f) || (mb[1] > m_run[1] + 8.f) ||
                  (mb[2] > m_run[2] + 8.f) || (mb[3] > m_run[3] + 8.f);
      if (__any(need)) {
        float fac[4];
#pragma unroll
        for (int q = 0; q < 4; ++q) {
          float mn = fmaxf(m_run[q], mb[q]);
          fac[q] = __expf(m_run[q] - mn);
          m_run[q] = mn;
          l_run[q] *= fac[q];
        }
#pragma unroll
        for (int hb = 0; hb < 8; ++hb)
#pragma unroll
          for (int q = 0; q < 4; ++q) oacc[hb][q] *= fac[q];
      }
#pragma unroll
      for (int j = 0; j < 4; ++j)
#pragma unroll
        for (int q = 0; q < 4; ++q) sc[j][q] = __expf(sc[j][q] - m_run[q]);
#pragma unroll
      for (int q = 0; q < 4; ++q)
        ls[q] = (sc[0][q] + sc[1][q]) + (sc[2][q] + sc[3][q]);
#pragma unroll
      for (int off = 1; off < 16; off <<= 1) {
#pragma unroll
        for (int q = 0; q < 4; ++q) ls[q] += __shfl_xor(ls[q], off);
      }
#pragma unroll
      for (int q = 0; q < 4; ++q) l_run[q] += ls[q];

      // ---- P: C-layout -> bf16 A-layout via per-wave swizzled LDS ----
#pragma unroll
      for (int j = 0; j < 4; ++j)
#pragma unroll
        for (int q = 0; q < 4; ++q) {
          int row = hi * 4 + q;
          int cb = ((j * 16 + lr) * 2) ^ ((row & 7) << 4);
          *(u16*)((char*)Pw + row * 128 + cb) = f2bf(sc[j][q]);
        }
      bf16x8 pf[2];
      {
        int rx = (lr & 7) << 4;
#pragma unroll
        for (int c = 0; c < 2; ++c)
          pf[c] = *(const bf16x8*)((const char*)Pw + lr * 128 + ((c * 64 + hi * 16) ^ rx));
      }

      // ---- PV from swizzled V tile ----
#pragma unroll
      for (int hb = 0; hb < 8; ++hb) {
        int h = hb * 16 + lr;
        int rx = (h & 7) << 4;
#pragma unroll
        for (int c = 0; c < 2; ++c) {
          bf16x8 vf = *(const bf16x8*)(kb + 16384 + h * 128 + ((c * 64 + hi * 16) ^ rx));
          oacc[hb] = __builtin_amdgcn_mfma_f32_16x16x32_bf16(pf[c], vf, oacc[hb], 0, 0, 0);
        }
      }

      asm volatile("s_waitcnt vmcnt(0)" ::: "memory");
      __syncthreads();
      cur ^= 1;
    }

    // ---- epilogue: normalize + store ----
#pragma unroll
    for (int hb = 0; hb < 8; ++hb)
#pragma unroll
      for (int q = 0; q < 4; ++q) {
        float val = oacc[hb][q] / l_run[q];
        O[((size_t)((b * Td + t0 + hi * 4 + q) * Nh + n)) * Hd + hb * 16 + lr] = f2bf(val);
      }
  }
}

// ---------------------------------------------------------------------------
extern "C" void kernel_launch(void* const* d_in, const int* in_sizes, int n_in,
                              void* d_out, int out_size, void* d_ws, size_t ws_size,
                              hipStream_t stream) {
  (void)in_sizes; (void)n_in; (void)out_size; (void)ws_size;
  const float* Xq  = (const float*)d_in[0];
  const float* Xkv = (const float*)d_in[1];
  const int* qpos  = (const int*)d_in[2];
  const int* kpos  = (const int*)d_in[3];
  const float* Wq  = (const float*)d_in[4];
  const float* Wk  = (const float*)d_in[5];
  const float* Wv  = (const float*)d_in[6];
  const float* Wo  = (const float*)d_in[7];
  float* out = (float*)d_out;

  char* ws = (char*)d_ws;
  size_t off = 0;
  auto take = [&](size_t bytes) -> char* {
    char* p = ws + off;
    off += (bytes + 255) & ~(size_t)255;
    return p;
  };
  const size_t nX   = (size_t)Bb * Td * Dd;        // 8,388,608
  const size_t nQ   = (size_t)Bb * Td * Nh * Hd;   // 8,388,608
  const size_t nKV  = (size_t)Bb * Sd * Kvh * Hd;  // 2,097,152
  const size_t nTab = (size_t)Bb * Td * 64;        // 262,144

  u16* XqB   = (u16*)take(nX * 2);                     // reused: attn out
  u16* XkvB  = (u16*)take(nX * 2);                     // reused as Vt
  u16* WqT   = (u16*)take((size_t)Nh * Hd * Dd * 2);
  u16* BtKV  = (u16*)take((size_t)(Kvh * Hd * 2) * Dd * 2);  // [1024][2048]
  u16* WoT   = (u16*)take((size_t)Dd * Nh * Hd * 2);
  float* Qf  = (float*)take(nQ * 4);                   // f32 Q (RoPE'd)
  u16* Kb    = (u16*)take(nKV * 2);                    // [B][Kvh][S][H]
  u16* Vb    = (u16*)take(nKV * 2);
  float* cosQ = (float*)take(nTab * 4);
  float* sinQ = (float*)take(nTab * 4);
  float* cosK = (float*)take(nTab * 4);
  float* sinK = (float*)take(nTab * 4);
  // Aliases (lifetimes sequenced):
  u16* attnB = XqB;          // attn output; XqB dead after Q-proj
  u16* Vt    = XkvB;         // XkvB dead after KV-proj

  k_convert<<<dim3((int)(nX / 8 / 256)), 256, 0, stream>>>(Xq, XqB, (int)(nX / 8));
  k_convert<<<dim3((int)(nX / 8 / 256)), 256, 0, stream>>>(Xkv, XkvB, (int)(nX / 8));
  k_transpose_f32_bf16<<<dim3((Nh * Hd) / 32, Dd / 32), 256, 0, stream>>>(Wq, WqT, Dd, Nh * Hd);
  k_transpose_f32_bf16<<<dim3((Kvh * Hd) / 32, Dd / 32), 256, 0, stream>>>(Wk, BtKV, Dd, Kvh * Hd);
  k_transpose_f32_bf16<<<dim3((Kvh * Hd) / 32, Dd / 32), 256, 0, stream>>>(
      Wv, BtKV + (size_t)512 * Dd, Dd, Kvh * Hd);
  k_transpose_f32_bf16<<<dim3(Dd / 32, (Nh * Hd) / 32), 256, 0, stream>>>(Wo, WoT, Nh * Hd, Dd);
  k_rope_tables<<<dim3((int)(nTab / 256)), 256, 0, stream>>>(qpos, cosQ, sinQ, (int)nTab);
  k_rope_tables<<<dim3((int)(nTab / 256)), 256, 0, stream>>>(kpos, cosK, sinK, (int)nTab);

  // Q projection + fused RoPE -> f32
  k_gemm_q<<<dim3((Bb * Td / 128) * ((Nh * Hd) / 128)), 256, 0, stream>>>(
      XqB, WqT, Qf, cosQ, sinQ);
  // merged K (RoPE + bf16, [B][Kvh][S][H]) + V (bf16) projection
  k_gemm_kv<<<dim3((Bb * Td / 128) * 8), 256, 0, stream>>>(
      XkvB, BtKV, Kb, Vb, cosK, sinK);

  k_transpose_v<<<dim3(Hd / 32, Sd / 32, Bb * Kvh), 256, 0, stream>>>(Vb, Vt);

  k_attn<<<dim3(Bb * Nh * 16), 256, 0, stream>>>(Qf, Kb, Vt, attnB);

  k_gemm_bt<<<dim3((Bb * Td / 128) * ((Nh * Hd) / 128)), 256, 0, stream>>>(
      attnB, WoT, out, Bb * Td, Nh * Hd, Dd);
}